// Round 9
// baseline (199.139 us; speedup 1.0000x reference)
//
#include <hip/hip_runtime.h>
#include <hip/hip_bf16.h>

#define NB 2
#define NS 2048
#define NDM 1024
#define NH 16
#define ND 64
#define NM (NB * NS)   // 4096
#define RS 3072        // qkv row stride
#define C1 0.1803368801111243f   // SCALE * log2(e)
#define THR_RAW 44.36141956f     // 8 / C1 : defer-max threshold in raw-score units

typedef __attribute__((ext_vector_type(8))) short bf16x8;    // MFMA A/B frag (4 VGPRs)
typedef __attribute__((ext_vector_type(4))) float f32x4;     // 16x16 C/D frag
typedef __attribute__((ext_vector_type(16))) float f32x16;   // 32x32 C/D frag

__device__ __forceinline__ unsigned short f2bf(float f) {
    unsigned int u = __float_as_uint(f);
    u += 0x7fffu + ((u >> 16) & 1u);   // RNE
    return (unsigned short)(u >> 16);
}

// async global->LDS, 16B per lane. LDS dest = wave-uniform base + lane*16.
__device__ __forceinline__ void gload16(const unsigned short* g, unsigned short* l) {
    __builtin_amdgcn_global_load_lds(
        (const __attribute__((address_space(1))) void*)g,
        (__attribute__((address_space(3))) void*)l, 16, 0, 0);
}

// ---------------------------------------------------------------------------
// fp32 -> bf16 elementwise
// ---------------------------------------------------------------------------
__global__ __launch_bounds__(256)
void convert_bf16(const float* __restrict__ in, unsigned short* __restrict__ out, int n8) {
    int i = blockIdx.x * 256 + threadIdx.x;
    const int stride = gridDim.x * 256;
    for (; i < n8; i += stride) {
        const float4 a = ((const float4*)in)[i * 2];
        const float4 b = ((const float4*)in)[i * 2 + 1];
        bf16x8 v;
        v[0] = (short)f2bf(a.x); v[1] = (short)f2bf(a.y);
        v[2] = (short)f2bf(a.z); v[3] = (short)f2bf(a.w);
        v[4] = (short)f2bf(b.x); v[5] = (short)f2bf(b.y);
        v[6] = (short)f2bf(b.z); v[7] = (short)f2bf(b.w);
        *(bf16x8*)(out + (size_t)i * 8) = v;
    }
}

// ---------------------------------------------------------------------------
// W[K][N] fp32 -> WT[N][K] bf16 (64x64 LDS-tiled)
// ---------------------------------------------------------------------------
__global__ __launch_bounds__(256)
void transpose_bf16(const float* __restrict__ W, unsigned short* __restrict__ WT,
                    int K, int N) {
    __shared__ float Ts[64][65];
    const int n0 = blockIdx.x * 64, k0 = blockIdx.y * 64;
    const int t = threadIdx.x;
    {
        const int c4 = (t & 15) * 4;
        #pragma unroll
        for (int p = 0; p < 4; p++) {
            const int r = (t >> 4) + p * 16;
            const float4 v = *(const float4*)(W + (size_t)(k0 + r) * N + n0 + c4);
            Ts[r][c4] = v.x; Ts[r][c4 + 1] = v.y; Ts[r][c4 + 2] = v.z; Ts[r][c4 + 3] = v.w;
        }
    }
    __syncthreads();
    {
        const int cc8 = (t & 7) * 8;
        #pragma unroll
        for (int p = 0; p < 2; p++) {
            const int rr = (t >> 3) + p * 32;
            bf16x8 v;
            #pragma unroll
            for (int j = 0; j < 8; j++) v[j] = (short)f2bf(Ts[cc8 + j][rr]);
            *(bf16x8*)(WT + (size_t)(n0 + rr) * K + k0 + cc8) = v;
        }
    }
}

// ---------------------------------------------------------------------------
// V columns of qkv [token][3072] -> vT [bh][d=64][s=2048], 64x64 tiles.
// ---------------------------------------------------------------------------
__global__ __launch_bounds__(256)
void vtrans(const unsigned short* __restrict__ qkvb, unsigned short* __restrict__ vT) {
    __shared__ unsigned short Ts[64][65];
    const int st = blockIdx.x, bh = blockIdx.y;
    const int h = bh & (NH - 1), b = bh >> 4;
    const int t = threadIdx.x;
    {
        const int c8 = (t & 7) * 8;
        #pragma unroll
        for (int p = 0; p < 2; p++) {
            const int r = (t >> 3) + p * 32;
            const unsigned short* src =
                qkvb + (size_t)(b * NS + st * 64 + r) * RS + 2 * NDM + h * ND + c8;
            const bf16x8 v = *(const bf16x8*)src;
            #pragma unroll
            for (int j = 0; j < 8; j++) Ts[r][c8 + j] = (unsigned short)v[j];
        }
    }
    __syncthreads();
    {
        #pragma unroll
        for (int i = 0; i < 2; i++) {
            const int u = t + i * 256;
            const int d = u >> 3, cg = (u & 7) * 8;
            bf16x8 v;
            #pragma unroll
            for (int j = 0; j < 8; j++) v[j] = (short)Ts[cg + j][d];
            *(bf16x8*)(vT + ((size_t)bh * ND + d) * NS + st * 64 + cg) = v;
        }
    }
}

// ---------------------------------------------------------------------------
// 128x128 GEMM, BK=32, double-buffered (1 barrier/K-step). bf16 in.
// MODE 0: fp32 C + bias. MODE 1: bf16 C + bias.
// ---------------------------------------------------------------------------
template<int MODE>
__global__ __launch_bounds__(256)
void gemm128(const unsigned short* __restrict__ A, const unsigned short* __restrict__ BT,
             const float* __restrict__ bias, void* __restrict__ Cv,
             int M, int N, int K) {
    __shared__ unsigned short As[2][128 * 32];
    __shared__ unsigned short Bs[2][128 * 32];

    const int t = threadIdx.x, lane = t & 63, wv = t >> 6;
    const int wm = wv >> 1, wn = wv & 1;
    const int m0 = blockIdx.y * 128, n0 = blockIdx.x * 128;
    const int fr = lane & 15, fg = lane >> 4;

    f32x4 acc[4][4];
    #pragma unroll
    for (int m = 0; m < 4; m++)
        #pragma unroll
        for (int n = 0; n < 4; n++)
            #pragma unroll
            for (int r = 0; r < 4; r++) acc[m][n][r] = 0.f;

#define GSTAGE(buf, kk)                                                               \
    {                                                                                 \
        _Pragma("unroll")                                                             \
        for (int i = 0; i < 2; i++) {                                                 \
            const int u = t + i * 256;                                                \
            const int row = u >> 2;                                                   \
            const int grp = (u & 3) ^ ((row ^ (row >> 2)) & 3);                       \
            gload16(A  + (size_t)(m0 + row) * K + (kk) + grp * 8,                     \
                    &As[buf][(i * 256 + wv * 64) * 8]);                               \
            gload16(BT + (size_t)(n0 + row) * K + (kk) + grp * 8,                     \
                    &Bs[buf][(i * 256 + wv * 64) * 8]);                               \
        }                                                                             \
    }

#define GCOMPUTE(buf)                                                                 \
    {                                                                                 \
        bf16x8 af[4], bfv[4];                                                         \
        _Pragma("unroll")                                                             \
        for (int m = 0; m < 4; m++) {                                                 \
            const int row = wm * 64 + m * 16 + fr;                                    \
            af[m] = *(const bf16x8*)&As[buf][row * 32 +                               \
                        ((fg ^ ((row ^ (row >> 2)) & 3)) << 3)];                      \
        }                                                                             \
        _Pragma("unroll")                                                             \
        for (int n = 0; n < 4; n++) {                                                 \
            const int row = wn * 64 + n * 16 + fr;                                    \
            bfv[n] = *(const bf16x8*)&Bs[buf][row * 32 +                              \
                        ((fg ^ ((row ^ (row >> 2)) & 3)) << 3)];                      \
        }                                                                             \
        __builtin_amdgcn_s_setprio(1);                                                \
        _Pragma("unroll")                                                             \
        for (int m = 0; m < 4; m++)                                                   \
            _Pragma("unroll")                                                         \
            for (int n = 0; n < 4; n++)                                               \
                acc[m][n] = __builtin_amdgcn_mfma_f32_16x16x32_bf16(                  \
                    af[m], bfv[n], acc[m][n], 0, 0, 0);                               \
        __builtin_amdgcn_s_setprio(0);                                                \
    }

    GSTAGE(0, 0);
    for (int k0 = 0; k0 < K; k0 += 64) {
        __syncthreads();
        GSTAGE(1, k0 + 32);
        GCOMPUTE(0);
        __syncthreads();
        if (k0 + 64 < K) GSTAGE(0, k0 + 64);
        GCOMPUTE(1);
    }
#undef GSTAGE
#undef GCOMPUTE

    #pragma unroll
    for (int m = 0; m < 4; m++)
        #pragma unroll
        for (int n = 0; n < 4; n++) {
            const int col = n0 + wn * 64 + n * 16 + fr;
            const float bb = bias[col];
            #pragma unroll
            for (int rg = 0; rg < 4; rg++) {
                const int row = m0 + wm * 64 + m * 16 + fg * 4 + rg;
                const float v = acc[m][n][rg] + bb;
                if (MODE == 0) ((float*)Cv)[(size_t)row * N + col] = v;
                else ((unsigned short*)Cv)[(size_t)row * N + col] = f2bf(v);
            }
        }
}

// ---------------------------------------------------------------------------
// 128x64 GEMM (gemm2: doubles blocks/CU). fp32 C + bias.
// ---------------------------------------------------------------------------
__global__ __launch_bounds__(256)
void gemm128x64(const unsigned short* __restrict__ A, const unsigned short* __restrict__ BT,
                const float* __restrict__ bias, float* __restrict__ C,
                int M, int N, int K) {
    __shared__ unsigned short As[2][128 * 32];   // 16 KB
    __shared__ unsigned short Bs[2][64 * 32];    //  8 KB

    const int t = threadIdx.x, lane = t & 63, wv = t >> 6;
    const int wm = wv >> 1, wn = wv & 1;
    const int m0 = blockIdx.y * 128, n0 = blockIdx.x * 64;
    const int fr = lane & 15, fg = lane >> 4;

    f32x4 acc[4][2];
    #pragma unroll
    for (int m = 0; m < 4; m++)
        #pragma unroll
        for (int n = 0; n < 2; n++)
            #pragma unroll
            for (int r = 0; r < 4; r++) acc[m][n][r] = 0.f;

#define G2STAGE(buf, kk)                                                              \
    {                                                                                 \
        _Pragma("unroll")                                                             \
        for (int i = 0; i < 2; i++) {                                                 \
            const int u = t + i * 256;                                                \
            const int row = u >> 2;                                                   \
            const int grp = (u & 3) ^ ((row ^ (row >> 2)) & 3);                       \
            gload16(A + (size_t)(m0 + row) * K + (kk) + grp * 8,                      \
                    &As[buf][(i * 256 + wv * 64) * 8]);                               \
        }                                                                             \
        {                                                                             \
            const int row = t >> 2;                                                   \
            const int grp = (t & 3) ^ ((row ^ (row >> 2)) & 3);                       \
            gload16(BT + (size_t)(n0 + row) * K + (kk) + grp * 8,                     \
                    &Bs[buf][(wv * 64) * 8]);                                         \
        }                                                                             \
    }

#define G2COMPUTE(buf)                                                                \
    {                                                                                 \
        bf16x8 af[4], bfv[2];                                                         \
        _Pragma("unroll")                                                             \
        for (int m = 0; m < 4; m++) {                                                 \
            const int row = wm * 64 + m * 16 + fr;                                    \
            af[m] = *(const bf16x8*)&As[buf][row * 32 +                               \
                        ((fg ^ ((row ^ (row >> 2)) & 3)) << 3)];                      \
        }                                                                             \
        _Pragma("unroll")                                                             \
        for (int n = 0; n < 2; n++) {                                                 \
            const int row = wn * 32 + n * 16 + fr;                                    \
            bfv[n] = *(const bf16x8*)&Bs[buf][row * 32 +                              \
                        ((fg ^ ((row ^ (row >> 2)) & 3)) << 3)];                      \
        }                                                                             \
        __builtin_amdgcn_s_setprio(1);                                                \
        _Pragma("unroll")                                                             \
        for (int m = 0; m < 4; m++)                                                   \
            _Pragma("unroll")                                                         \
            for (int n = 0; n < 2; n++)                                               \
                acc[m][n] = __builtin_amdgcn_mfma_f32_16x16x32_bf16(                  \
                    af[m], bfv[n], acc[m][n], 0, 0, 0);                               \
        __builtin_amdgcn_s_setprio(0);                                                \
    }

    G2STAGE(0, 0);
    for (int k0 = 0; k0 < K; k0 += 64) {
        __syncthreads();
        G2STAGE(1, k0 + 32);
        G2COMPUTE(0);
        __syncthreads();
        if (k0 + 64 < K) G2STAGE(0, k0 + 64);
        G2COMPUTE(1);
    }
#undef G2STAGE
#undef G2COMPUTE

    #pragma unroll
    for (int m = 0; m < 4; m++)
        #pragma unroll
        for (int n = 0; n < 2; n++) {
            const int col = n0 + wn * 32 + n * 16 + fr;
            const float bb = bias[col];
            #pragma unroll
            for (int rg = 0; rg < 4; rg++) {
                const int row = m0 + wm * 64 + m * 16 + fg * 4 + rg;
                C[(size_t)row * N + col] = acc[m][n][rg] + bb;
            }
        }
}

// ---------------------------------------------------------------------------
// Causal flash attention, 32x32 MFMA, fully in-register P.
// S^T = mfma(K,Q): lane holds 32 S-values of ONE q (col=lane&31) -> in-lane
// softmax, 1 shfl per reduce. P packed via cvt_pk, PV B-frags assembled with
// 8 shfl_xor(32) + cndmask (no P LDS). O^T = mfma(V^T,P^T): per-lane q state
// everywhere. QBLK=128 (4 waves x 32 q), KVBLK=64, double-buffered,
// 1 barrier/tile, LPT. LDS 32 KB.
// ---------------------------------------------------------------------------
__global__ __launch_bounds__(256)
void attn_mfma(const unsigned short* __restrict__ qkvb, const unsigned short* __restrict__ vT,
               unsigned short* __restrict__ atto) {
    const int bx = blockIdx.x;
    const int qt = (NS / 128 - 1) - (bx >> 5);   // 15..0 (longest first)
    const int bh = bx & 31;
    const int h = bh & (NH - 1), b = bh >> 4;
    const int q0 = qt * 128;
    const int t = threadIdx.x, lane = t & 63, wv = t >> 6;
    const int l31 = lane & 31, hf = lane >> 5;
    const bool hb = hf != 0;

    __shared__ unsigned short Kt[2][64 * 64];   // [key][d], 8 KB each
    __shared__ unsigned short Vt[2][64 * 64];   // [d][key], 8 KB each

    const unsigned short* kb = qkvb + (size_t)b * NS * RS + NDM + h * ND;
    const unsigned short* vb = vT + (size_t)bh * ND * NS;

    // Q B-frags: lane (l31=q, hf) holds Q[q0+wv*32+l31][kd*16+hf*8+{0..7}]
    bf16x8 qf[4];
    {
        const unsigned short* qrow =
            qkvb + (size_t)(b * NS + q0 + wv * 32 + l31) * RS + h * ND + hf * 8;
        qf[0] = *(const bf16x8*)(qrow);
        qf[1] = *(const bf16x8*)(qrow + 16);
        qf[2] = *(const bf16x8*)(qrow + 32);
        qf[3] = *(const bf16x8*)(qrow + 48);
    }

    f32x16 oacc[2];
    #pragma unroll
    for (int d2 = 0; d2 < 2; d2++)
        #pragma unroll
        for (int r = 0; r < 16; r++) oacc[d2][r] = 0.f;
    float mrow = -INFINITY;   // running raw max for q = l31 (replicated across hf)
    float nmC  = INFINITY;    // -mrow*C1
    float lrow = 0.f;

    const int ntiles = 2 * qt + 2;

#define STAGE_KV(cbuf, jtile)                                                        \
    {                                                                                \
        _Pragma("unroll")                                                            \
        for (int i = 0; i < 2; i++) {                                                \
            const int u = t + i * 256;                                               \
            const int row = u >> 3;                                                  \
            const int gs = (u & 7) ^ (row & 7);                                      \
            gload16(kb + (size_t)((jtile) * 64 + row) * RS + gs * 8,                 \
                    &Kt[cbuf][(i * 256 + wv * 64) * 8]);                             \
        }                                                                            \
        _Pragma("unroll")                                                            \
        for (int i = 0; i < 2; i++) {                                                \
            const int u = t + i * 256;                                               \
            const int row = u >> 3;                                                  \
            const int gs = (u & 7) ^ (row & 7);                                      \
            gload16(vb + (size_t)row * NS + (jtile) * 64 + gs * 8,                   \
                    &Vt[cbuf][(i * 256 + wv * 64) * 8]);                             \
        }                                                                            \
    }

    STAGE_KV(0, 0);

    for (int jt = 0; jt < ntiles; jt++) {
        const int cur = jt & 1;
        __syncthreads();   // drains vmcnt (stage of cur done) + read-fence on cur^1
        if (jt + 1 < ntiles) STAGE_KV(cur ^ 1, jt + 1);
        const unsigned short* Ktc = Kt[cur];
        const unsigned short* Vtc = Vt[cur];

        // ---- S^T = K Q^T: sacc[kb2][r] = S[key=kb2*32+(r&3)+8(r>>2)+4hf][q=l31]
        f32x16 sacc[2];
        #pragma unroll
        for (int kb2 = 0; kb2 < 2; kb2++)
            #pragma unroll
            for (int r = 0; r < 16; r++) sacc[kb2][r] = 0.f;
        __builtin_amdgcn_s_setprio(1);
        #pragma unroll
        for (int kb2 = 0; kb2 < 2; kb2++) {
            const int row = kb2 * 32 + l31;
            #pragma unroll
            for (int kd = 0; kd < 4; kd++) {
                const int s = (2 * kd + hf) ^ (row & 7);
                const bf16x8 kf = *(const bf16x8*)&Ktc[row * 64 + s * 8];
                sacc[kb2] = __builtin_amdgcn_mfma_f32_32x32x16_bf16(
                    kf, qf[kd], sacc[kb2], 0, 0, 0);
            }
        }
        __builtin_amdgcn_s_setprio(0);

        if (jt >= ntiles - 2) {   // last two tiles can cross the diagonal
            const int qg = q0 + wv * 32 + l31;
            #pragma unroll
            for (int kb2 = 0; kb2 < 2; kb2++)
                #pragma unroll
                for (int r = 0; r < 16; r++) {
                    const int key = jt * 64 + kb2 * 32 + (r & 3) + 8 * (r >> 2) + 4 * hf;
                    if (key > qg) sacc[kb2][r] = -INFINITY;
                }
        }

        // ---- in-lane row max (32 vals) + 1 shfl
        float pm = sacc[0][0];
        #pragma unroll
        for (int r = 1; r < 16; r++) pm = fmaxf(pm, sacc[0][r]);
        #pragma unroll
        for (int r = 0; r < 16; r++) pm = fmaxf(pm, sacc[1][r]);
        pm = fmaxf(pm, __shfl_xor(pm, 32));

        // ---- defer-max rescale
        if (__any(pm > mrow + THR_RAW)) {
            const float mn = fmaxf(mrow, pm);
            const float alpha = __builtin_amdgcn_exp2f((mrow - mn) * C1);
            mrow = mn;
            nmC = -mn * C1;
            lrow *= alpha;
            #pragma unroll
            for (int d2 = 0; d2 < 2; d2++)
                #pragma unroll
                for (int r = 0; r < 16; r++) oacc[d2][r] *= alpha;
        }

        // ---- P = exp2(S*C1 + nmC), in-lane sum + 1 shfl
        float psum = 0.f;
        #pragma unroll
        for (int kb2 = 0; kb2 < 2; kb2++)
            #pragma unroll
            for (int r = 0; r < 16; r++) {
                const float p = __builtin_amdgcn_exp2f(fmaf(sacc[kb2][r], C1, nmC));
                sacc[kb2][r] = p;
                psum += p;
            }
        psum += __shfl_xor(psum, 32);
        lrow += psum;

        // ---- pack P to bf16 pairs: W[kb2][r2][c] = keys kb2*32+8r2+4hf+2c+{0,1}
        unsigned int W[2][4][2];
        #pragma unroll
        for (int kb2 = 0; kb2 < 2; kb2++)
            #pragma unroll
            for (int r2 = 0; r2 < 4; r2++)
                #pragma unroll
                for (int c = 0; c < 2; c++)
                    asm("v_cvt_pk_bf16_f32 %0, %1, %2" : "=v"(W[kb2][r2][c])
                        : "v"(sacc[kb2][r2 * 4 + c * 2]), "v"(sacc[kb2][r2 * 4 + c * 2 + 1]));

        // ---- assemble PV B-frags in registers (keys ks*16+hf*8+{0..7}, q=l31)
        bf16x8 pf[4];
        #pragma unroll
        for (int ks = 0; ks < 4; ks++) {
            const int kb2 = ks >> 1, s = ks & 1;
            const unsigned int X0 = hb ? W[kb2][2 * s][0] : W[kb2][2 * s + 1][0];
            const unsigned int X1 = hb ? W[kb2][2 * s][1] : W[kb2][2 * s + 1][1];
            const unsigned int Y0 = __shfl_xor(X0, 32);
            const unsigned int Y1 = __shfl_xor(X1, 32);
            unsigned int u[4];
            u[0] = hb ? Y0 : W[kb2][2 * s][0];
            u[1] = hb ? Y1 : W[kb2][2 * s][1];
            u[2] = hb ? W[kb2][2 * s + 1][0] : Y0;
            u[3] = hb ? W[kb2][2 * s + 1][1] : Y1;
            pf[ks] = *(bf16x8*)u;
        }

        // ---- O^T += V^T P^T
        __builtin_amdgcn_s_setprio(1);
        #pragma unroll
        for (int d2 = 0; d2 < 2; d2++) {
            const int row = d2 * 32 + l31;
            #pragma unroll
            for (int ks = 0; ks < 4; ks++) {
                const int s = (2 * ks + hf) ^ (row & 7);
                const bf16x8 vf = *(const bf16x8*)&Vtc[row * 64 + s * 8];
                oacc[d2] = __builtin_amdgcn_mfma_f32_32x32x16_bf16(
                    vf, pf[ks], oacc[d2], 0, 0, 0);
            }
        }
        __builtin_amdgcn_s_setprio(0);
    }
#undef STAGE_KV

    // ---- epilogue: lane holds O^T[d][q=l31]; divide in-lane, pack, u32 stores
    const float inv = 1.f / lrow;
    const int q = q0 + wv * 32 + l31;
    unsigned short* dst = atto + ((size_t)b * NS + q) * NDM + h * ND;
    #pragma unroll
    for (int d2 = 0; d2 < 2; d2++)
        #pragma unroll
        for (int r2 = 0; r2 < 4; r2++)
            #pragma unroll
            for (int c = 0; c < 2; c++) {
                unsigned int w;
                const float a0 = oacc[d2][r2 * 4 + c * 2] * inv;
                const float a1 = oacc[d2][r2 * 4 + c * 2 + 1] * inv;
                asm("v_cvt_pk_bf16_f32 %0, %1, %2" : "=v"(w) : "v"(a0), "v"(a1));
                *(unsigned int*)&dst[d2 * 32 + r2 * 8 + hf * 4 + c * 2] = w;
            }
}

// ---------------------------------------------------------------------------
extern "C" void kernel_launch(void* const* d_in, const int* in_sizes, int n_in,
                              void* d_out, int out_size, void* d_ws, size_t ws_size,
                              hipStream_t stream) {
    const float* x     = (const float*)d_in[0];
    const float* w_qkv = (const float*)d_in[1];
    const float* b_qkv = (const float*)d_in[2];
    const float* w_out = (const float*)d_in[3];
    const float* b_out = (const float*)d_in[4];
    float* out = (float*)d_out;

    unsigned short* xb   = (unsigned short*)d_ws;             //  8 MB (aliased by atto)
    unsigned short* wqT  = xb   + (size_t)NM * NDM;           //  6 MB [3072][1024]
    unsigned short* woT  = wqT  + (size_t)3 * NDM * NDM;      //  2 MB [1024][1024]
    unsigned short* qkvb = woT  + (size_t)NDM * NDM;          // 24 MB [4096][3072]
    unsigned short* vT   = qkvb + (size_t)NM * 3 * NDM;       //  8 MB [32][64][2048]
    unsigned short* atto = xb;                                //  alias: xb dead after gemm1

    convert_bf16<<<2048, 256, 0, stream>>>(x, xb, NM * NDM / 8);
    transpose_bf16<<<dim3(3 * NDM / 64, NDM / 64), 256, 0, stream>>>(w_qkv, wqT, NDM, 3 * NDM);
    transpose_bf16<<<dim3(NDM / 64, NDM / 64), 256, 0, stream>>>(w_out, woT, NDM, NDM);

    // 1) qkv = x @ w_qkv + b   (bf16, row-major)
    gemm128<1><<<dim3(3 * NDM / 128, NM / 128), 256, 0, stream>>>(
        xb, wqT, b_qkv, qkvb, NM, 3 * NDM, NDM);

    // 1b) vT = transpose of v columns
    vtrans<<<dim3(NS / 64, NB * NH), 256, 0, stream>>>(qkvb, vT);

    // 2) causal flash attention (32x32 MFMA, in-register P)
    attn_mfma<<<dim3((NS / 128) * NB * NH), 256, 0, stream>>>(qkvb, vT, atto);

    // 3) out = atto @ w_out + b  (fp32 out)
    gemm128x64<<<dim3(NDM / 64, NM / 128), 256, 0, stream>>>(
        atto, woT, b_out, out, NM, NDM, NDM);
}